// Round 1
// baseline (850.334 us; speedup 1.0000x reference)
//
#include <hip/hip_runtime.h>
#include <stdint.h>

#define B_ 1024
#define T_ 512
#define F_ 64
#define H_ 32
#define G_ 128  // 4H

__device__ __forceinline__ uint32_t bf16r(float f) {
  uint32_t u = __builtin_bit_cast(uint32_t, f);
  return (u + 0x7fffu + ((u >> 16) & 1u)) >> 16;  // RNE bf16
}
__device__ __forceinline__ float rl(float v, int l) {
  return __builtin_bit_cast(float, __builtin_amdgcn_readlane(__builtin_bit_cast(int, v), l));
}
__device__ __forceinline__ float fsig(float x) { return 1.f / (1.f + __expf(-x)); }
__device__ __forceinline__ float ftanh(float x) { return 2.f / (1.f + __expf(-2.f * x)) - 1.f; }

// ---------------------------------------------------------------------------
// K1: xg[b][t][j] = pack_bf16( G[j], G[j+64] ),  G = tanh(x@W_enc + b_enc)@kernel + bias
// One thread per (b,t) row. x staged transposed in LDS; weights broadcast from LDS.
// ---------------------------------------------------------------------------
__global__ __launch_bounds__(256, 1) void k1_encxg(
    const float* __restrict__ x, const float* __restrict__ Wenc,
    const float* __restrict__ benc, const float* __restrict__ kern,
    const float* __restrict__ bias, uint32_t* __restrict__ xg) {
  __shared__ float sW[F_ * F_];     // 16 KB
  __shared__ float sK[F_ * G_];     // 32 KB
  __shared__ float sX[F_ * 257];    // 65.8 KB, transposed x tile [k][row], pad 257
  const int tid = threadIdx.x;

  for (int i = tid; i < F_ * F_; i += 256) sW[i] = Wenc[i];
  for (int i = tid; i < F_ * G_; i += 256) sK[i] = kern[i];

  const int r0 = blockIdx.x * 256;  // row = b*512 + t
  const float4* x4 = (const float4*)(x + (size_t)r0 * F_);
  for (int i4 = tid; i4 < 256 * F_ / 4; i4 += 256) {
    float4 v = x4[i4];
    int r = i4 >> 4;
    int k0 = (i4 & 15) * 4;
    sX[(k0 + 0) * 257 + r] = v.x;
    sX[(k0 + 1) * 257 + r] = v.y;
    sX[(k0 + 2) * 257 + r] = v.z;
    sX[(k0 + 3) * 257 + r] = v.w;
  }
  __syncthreads();

  // pass 1: enc = tanh(x @ W_enc + b_enc)
  float enc[F_];
#pragma unroll
  for (int j4 = 0; j4 < 16; ++j4) {
    float4 b = ((const float4*)benc)[j4];
    enc[j4 * 4 + 0] = b.x; enc[j4 * 4 + 1] = b.y;
    enc[j4 * 4 + 2] = b.z; enc[j4 * 4 + 3] = b.w;
  }
  for (int k = 0; k < F_; ++k) {
    float xk = sX[k * 257 + tid];
#pragma unroll
    for (int j4 = 0; j4 < 16; ++j4) {
      float4 w = *(const float4*)(&sW[k * F_ + j4 * 4]);  // uniform -> broadcast
      enc[j4 * 4 + 0] += xk * w.x; enc[j4 * 4 + 1] += xk * w.y;
      enc[j4 * 4 + 2] += xk * w.z; enc[j4 * 4 + 3] += xk * w.w;
    }
  }
#pragma unroll
  for (int j = 0; j < F_; ++j) enc[j] = ftanh(enc[j]);

  // park enc in LDS (own column only) so pass-2 can index it with a runtime j
#pragma unroll
  for (int j = 0; j < F_; ++j) sX[j * 257 + tid] = enc[j];
  __syncthreads();

  // pass 2: G = enc @ kernel + bias  (128 accumulators, static-indexed)
  float acc[G_];
#pragma unroll
  for (int n4 = 0; n4 < 32; ++n4) {
    float4 b = ((const float4*)bias)[n4];
    acc[n4 * 4 + 0] = b.x; acc[n4 * 4 + 1] = b.y;
    acc[n4 * 4 + 2] = b.z; acc[n4 * 4 + 3] = b.w;
  }
  for (int j = 0; j < F_; ++j) {
    float ej = sX[j * 257 + tid];
#pragma unroll
    for (int n4 = 0; n4 < 32; ++n4) {
      float4 w = *(const float4*)(&sK[j * G_ + n4 * 4]);  // uniform -> broadcast
      acc[n4 * 4 + 0] += ej * w.x; acc[n4 * 4 + 1] += ej * w.y;
      acc[n4 * 4 + 2] += ej * w.z; acc[n4 * 4 + 3] += ej * w.w;
    }
  }

  // pack (n, n+64) pairs as bf16x2 so the scan's lane j gets (z[j], z[j+64]) in one dword
  uint32_t* op = xg + (size_t)(r0 + tid) * 64;
#pragma unroll
  for (int q = 0; q < 16; ++q) {
    uint4 o;
    o.x = bf16r(acc[q * 4 + 0]) | (bf16r(acc[q * 4 + 0 + 64]) << 16);
    o.y = bf16r(acc[q * 4 + 1]) | (bf16r(acc[q * 4 + 1 + 64]) << 16);
    o.z = bf16r(acc[q * 4 + 2]) | (bf16r(acc[q * 4 + 2 + 64]) << 16);
    o.w = bf16r(acc[q * 4 + 3]) | (bf16r(acc[q * 4 + 3 + 64]) << 16);
    ((uint4*)op)[q] = o;
  }
}

// ---------------------------------------------------------------------------
// K2: LSTM scan + online attention softmax-pool + decode. One wave per batch.
// Lane j owns z[j] (i/f) and z[j+64] (g/o). h broadcast via v_readlane.
// ---------------------------------------------------------------------------
__global__ __launch_bounds__(64, 1) void k2_scan(
    const uint32_t* __restrict__ xg, const float* __restrict__ rec,
    const float* __restrict__ attnW, const float* __restrict__ attnB,
    const float* __restrict__ attnU, const float* __restrict__ Wdec,
    const float* __restrict__ bdec, float* __restrict__ out) {
  const int lane = threadIdx.x;
  const int b = blockIdx.x;
  const int lh = lane & 31;
  const bool lo32 = (lane < 32);

  float rA[H_], rB[H_], aW[H_];
#pragma unroll
  for (int k = 0; k < H_; ++k) {
    rA[k] = rec[k * G_ + lane];        // columns 0..63   (i|f)
    rB[k] = rec[k * G_ + 64 + lane];   // columns 64..127 (g|o)
    aW[k] = attnW[k * H_ + lh];
  }
  const float u_l = attnU[lh];
  const float ab_l = attnB[lh];
  const float wd1 = Wdec[lh];
  const float wd2 = Wdec[H_ + lh];
  const float bd = bdec[0];

  const uint32_t* xp = xg + (size_t)b * (T_ * 64) + lane;

  float h = 0.f, c = 0.f;
  float m = -1e30f, l = 0.f, p = 0.f;

  auto step = [&](uint32_t w, int t) {
    float z1 = __builtin_bit_cast(float, w << 16);          // z[lane]
    float z2 = __builtin_bit_cast(float, w & 0xffff0000u);  // z[lane+64]
    float lat = ab_l;
#pragma unroll
    for (int k = 0; k < H_; ++k) {
      float s = rl(h, k);
      z1 += s * rA[k];
      z2 += s * rB[k];
      lat += s * aW[k];
    }
    if (t > 0) {  // attention update for h_{t-1} (h register not yet overwritten)
      float tl = ftanh(lat);
      float v = tl * u_l;
      v += __shfl_xor(v, 1); v += __shfl_xor(v, 2); v += __shfl_xor(v, 4);
      v += __shfl_xor(v, 8); v += __shfl_xor(v, 16);
      float mn = fmaxf(m, v);
      float sc = __expf(m - mn), we = __expf(v - mn);
      l = l * sc + we;
      p = p * sc + we * h;
      m = mn;
    }
    float act1 = fsig(z1);                         // i (lane<32) | f (lane>=32)
    float xx = lo32 ? 2.f * z2 : z2;
    float sg = fsig(xx);
    float act2 = lo32 ? 2.f * sg - 1.f : sg;       // tanh(g) | sigmoid(o)
    float f = __shfl(act1, lane | 32);
    float o = __shfl(act2, lane | 32);
    c = f * c + act1 * act2;                       // valid on lanes<32
    float tc = ftanh(c);
    h = o * tc;
  };

  uint32_t c0 = xp[0 * 64], c1 = xp[1 * 64], c2 = xp[2 * 64], c3 = xp[3 * 64];
  for (int tb = 0; tb < T_; tb += 4) {
    uint32_t n0 = xp[((tb + 4) & 511) * 64];  // wrap keeps reads in-batch; values unused on last iter
    uint32_t n1 = xp[((tb + 5) & 511) * 64];
    uint32_t n2 = xp[((tb + 6) & 511) * 64];
    uint32_t n3 = xp[((tb + 7) & 511) * 64];
    step(c0, tb + 0);
    step(c1, tb + 1);
    step(c2, tb + 2);
    step(c3, tb + 3);
    c0 = n0; c1 = n1; c2 = n2; c3 = n3;
  }

  // attention update for final h (t = 511)
  {
    float lat = ab_l;
#pragma unroll
    for (int k = 0; k < H_; ++k) lat += rl(h, k) * aW[k];
    float tl = ftanh(lat);
    float v = tl * u_l;
    v += __shfl_xor(v, 1); v += __shfl_xor(v, 2); v += __shfl_xor(v, 4);
    v += __shfl_xor(v, 8); v += __shfl_xor(v, 16);
    float mn = fmaxf(m, v);
    float sc = __expf(m - mn), we = __expf(v - mn);
    l = l * sc + we;
    p = p * sc + we * h;
  }

  float pooled = p / l;
  float val = h * wd1 + pooled * wd2;
  val += __shfl_xor(val, 1); val += __shfl_xor(val, 2); val += __shfl_xor(val, 4);
  val += __shfl_xor(val, 8); val += __shfl_xor(val, 16);
  if (lane == 0) out[b] = fsig(val + bd);
}

extern "C" void kernel_launch(void* const* d_in, const int* in_sizes, int n_in,
                              void* d_out, int out_size, void* d_ws, size_t ws_size,
                              hipStream_t stream) {
  const float* x     = (const float*)d_in[0];
  const float* Wenc  = (const float*)d_in[1];
  const float* benc  = (const float*)d_in[2];
  const float* kern  = (const float*)d_in[3];
  const float* rec   = (const float*)d_in[4];
  const float* bias  = (const float*)d_in[5];
  const float* attnW = (const float*)d_in[6];
  const float* attnB = (const float*)d_in[7];
  const float* attnU = (const float*)d_in[8];
  const float* Wdec  = (const float*)d_in[9];
  const float* bdec  = (const float*)d_in[10];

  uint32_t* xg = (uint32_t*)d_ws;  // [B][T][64] packed bf16 pairs = 128 MiB

  hipLaunchKernelGGL(k1_encxg, dim3((B_ * T_) / 256), dim3(256), 0, stream,
                     x, Wenc, benc, kern, bias, xg);
  hipLaunchKernelGGL(k2_scan, dim3(B_), dim3(64), 0, stream,
                     xg, rec, attnW, attnB, attnU, Wdec, bdec, (float*)d_out);
}